// Round 6
// baseline (323.233 us; speedup 1.0000x reference)
//
#include <hip/hip_runtime.h>
#include <math.h>

#define D_MODEL 1024
#define HIDDEN  2048
#define D_STATE 16
#define BATCH   2
#define SEQ     2048
#define NTOK    (BATCH*SEQ)   // 4096
#define CHUNK   64
#define NCHUNK  (SEQ/CHUNK)   // 32

typedef __attribute__((ext_vector_type(8))) short bf16x8;
typedef __attribute__((ext_vector_type(8))) unsigned short ushort8;
typedef __attribute__((ext_vector_type(4))) float f32x4;

#define GLOAD_LDS16(gptr, lptr) \
    __builtin_amdgcn_global_load_lds((const __attribute__((address_space(1))) void*)(gptr), \
                                     (__attribute__((address_space(3))) void*)(lptr), 16, 0, 0)

__device__ __forceinline__ float softplus_f(float x) {
    return fmaxf(x, 0.0f) + log1pf(expf(-fabsf(x)));
}
__device__ __forceinline__ float sigmoid_f(float x) {
    return 1.0f / (1.0f + expf(-x));
}
__device__ __forceinline__ ushort f2bf(float f) {      // RNE fp32->bf16
    unsigned u = __float_as_uint(f);
    unsigned r = (u + 0x7fffu + ((u >> 16) & 1u)) >> 16;
    return (ushort)r;
}
__device__ __forceinline__ float bf2f(ushort u) {
    return __uint_as_float(((unsigned)u) << 16);
}

// Converts x, W_x, W_g, W_dt, W_out into a contiguous bf16 arena.
__global__ __launch_bounds__(256) void cvt_all(
    const float* __restrict__ x, const float* __restrict__ Wx,
    const float* __restrict__ Wg, const float* __restrict__ Wdt,
    const float* __restrict__ Wout, ushort* __restrict__ arena)
{
    int i = blockIdx.x * 256 + threadIdx.x;   // float4 index, total 3145728
    const float* src; int base;
    if      (i < 1048576) { src = x;    base = 0; }
    else if (i < 1572864) { src = Wx;   base = 1048576; }
    else if (i < 2097152) { src = Wg;   base = 1572864; }
    else if (i < 2621440) { src = Wdt;  base = 2097152; }
    else                  { src = Wout; base = 2621440; }
    float4 v = reinterpret_cast<const float4*>(src)[i - base];
    ushort4 o = { f2bf(v.x), f2bf(v.y), f2bf(v.z), f2bf(v.w) };
    reinterpret_cast<ushort4*>(arena)[i] = o;
}

// Double-buffered 128x128 K-loop (4 waves), BK=32. Same as R5 (verified).
__device__ __forceinline__ void kloop_dbuf(
    const ushort* __restrict__ A, const ushort* __restrict__ B,
    int K, int m0, int n0, ushort* As, ushort* Bs,
    f32x4 (&acc)[4][4], int lane, int w, int wm, int wn)
{
    const int lr   = lane >> 2;
    const int kc   = (lane & 3) * 8;
    const int quad = lane >> 4;
    const int fr   = lane & 15;

    const int slab0 = w * 2;
    const int r0 = slab0 * 16 + lr;
    const int r1 = r0 + 16;
    const size_t ga0 = (size_t)(m0 + r0) * K + kc;
    const size_t ga1 = (size_t)(m0 + r1) * K + kc;
    const size_t gb0 = (size_t)(n0 + r0) * K + kc;
    const size_t gb1 = (size_t)(n0 + r1) * K + kc;

    GLOAD_LDS16(A + ga0, &As[slab0 * 512]);
    GLOAD_LDS16(A + ga1, &As[slab0 * 512 + 512]);
    GLOAD_LDS16(B + gb0, &Bs[slab0 * 512]);
    GLOAD_LDS16(B + gb1, &Bs[slab0 * 512 + 512]);

    int buf = 0;
    for (int k0 = 0; k0 < K; k0 += 32) {
        __syncthreads();
        if (k0 + 32 < K) {
            const int nb = (buf ^ 1) * 4096;
            GLOAD_LDS16(A + ga0 + k0 + 32, &As[nb + slab0 * 512]);
            GLOAD_LDS16(A + ga1 + k0 + 32, &As[nb + slab0 * 512 + 512]);
            GLOAD_LDS16(B + gb0 + k0 + 32, &Bs[nb + slab0 * 512]);
            GLOAD_LDS16(B + gb1 + k0 + 32, &Bs[nb + slab0 * 512 + 512]);
        }
        const ushort* as = &As[buf * 4096];
        const ushort* bs = &Bs[buf * 4096];
        bf16x8 af[4], bfv[4];
        #pragma unroll
        for (int t = 0; t < 4; t++) {
            af[t]  = *reinterpret_cast<const bf16x8*>(&as[(wm * 64 + t * 16 + fr) * 32 + quad * 8]);
            bfv[t] = *reinterpret_cast<const bf16x8*>(&bs[(wn * 64 + t * 16 + fr) * 32 + quad * 8]);
        }
        #pragma unroll
        for (int i = 0; i < 4; i++)
            #pragma unroll
            for (int j = 0; j < 4; j++)
                acc[i][j] = __builtin_amdgcn_mfma_f32_16x16x32_bf16(af[i], bfv[j], acc[i][j], 0, 0, 0);
        buf ^= 1;
    }
}

// Fused projection GEMM. Grid is (m, n) with m fastest so consecutive blocks
// share the same B (weight) tile in L2.
__global__ __launch_bounds__(256) void proj_gemm_fused(
    const ushort* __restrict__ xbf, const ushort* __restrict__ Wcat,
    const float* __restrict__ b_x, const float* __restrict__ b_g,
    const float* __restrict__ b_dt, ushort* __restrict__ u_out,
    ushort* __restrict__ g_out, float* __restrict__ dt_sum)
{
    __shared__ ushort S[16384];            // 32KB: As(2buf)|Bs(2buf), reused as C tile
    ushort* As = S;
    ushort* Bs = S + 8192;
    const int tid = threadIdx.x, lane = tid & 63, w = tid >> 6;
    const int wm = w & 1, wn = w >> 1;
    const int m0 = blockIdx.x * 128, n0 = blockIdx.y * 128;   // m-fast grid
    const int quad = lane >> 4, fr = lane & 15;

    f32x4 acc[4][4];
    #pragma unroll
    for (int i = 0; i < 4; i++)
        #pragma unroll
        for (int j = 0; j < 4; j++)
            acc[i][j] = (f32x4){0.f, 0.f, 0.f, 0.f};

    kloop_dbuf(xbf, Wcat, D_MODEL, m0, n0, As, Bs, acc, lane, w, wm, wn);

    const int region = n0 >> 11;           // 0:u 1:g 2:dt
    const int ncb = n0 & 2047;

    if (region == 2) {
        #pragma unroll
        for (int j = 0; j < 4; j++) {
            int n = ncb + wn * 64 + j * 16 + fr;
            float bj = b_dt[n];
            float s = 0.f;
            #pragma unroll
            for (int i = 0; i < 4; i++)
                #pragma unroll
                for (int r = 0; r < 4; r++)
                    s += softplus_f(acc[i][j][r] + bj);
            s += __shfl_xor(s, 16);
            s += __shfl_xor(s, 32);
            if (lane < 16) atomicAdd(&dt_sum[n], s);
        }
    } else {
        const float* bias = region ? b_g : b_x;
        ushort* out = region ? g_out : u_out;
        __syncthreads();
        ushort* Cs = S;                    // [128][128] bf16 = 32KB
        #pragma unroll
        for (int j = 0; j < 4; j++) {
            int col = wn * 64 + j * 16 + fr;
            float bj = bias[ncb + col];
            #pragma unroll
            for (int i = 0; i < 4; i++) {
                int row = wm * 64 + i * 16 + quad * 4;
                #pragma unroll
                for (int r = 0; r < 4; r++) {
                    float v = acc[i][j][r] + bj;
                    if (region) v = sigmoid_f(v);
                    Cs[(row + r) * 128 + col] = f2bf(v);
                }
            }
        }
        __syncthreads();
        #pragma unroll
        for (int k = 0; k < 8; k++) {
            int v = k * 256 + tid;
            int row = v >> 4, c = (v & 15) * 8;
            *reinterpret_cast<ushort8*>(&out[(size_t)(m0 + row) * HIDDEN + ncb + c]) =
                *reinterpret_cast<const ushort8*>(&Cs[v * 8]);
        }
    }
}

// Out projection, re-tiled 64x128 (128 threads, 2 waves) for 2x block count:
// grid (64 m-tiles, 8 n-tiles), m fastest. resid = C + b_out + x (fp32).
__global__ __launch_bounds__(128) void gemm_out(
    const ushort* __restrict__ ybf, const ushort* __restrict__ Wout,
    const float* __restrict__ b_out, const float* __restrict__ x,
    float* __restrict__ resid)
{
    __shared__ ushort S[16384];            // 32KB; K-loop uses 24KB, epi 32KB
    ushort* As = S;                        // 2 x 2048 ushorts
    ushort* Bs = S + 4096;                 // 2 x 4096 ushorts
    const int tid = threadIdx.x, lane = tid & 63, w = tid >> 6;  // w in {0,1}
    const int wn = w;
    const int m0 = blockIdx.x * 64, n0 = blockIdx.y * 128;
    const int quad = lane >> 4, fr = lane & 15;
    const int lr = lane >> 2, kc = (lane & 3) * 8;
    const int K = HIDDEN;

    f32x4 acc[4][4];
    #pragma unroll
    for (int i = 0; i < 4; i++)
        #pragma unroll
        for (int j = 0; j < 4; j++)
            acc[i][j] = (f32x4){0.f, 0.f, 0.f, 0.f};

    // staging addresses: A rows 64 (2 slabs/wave), B rows 128 (4 slabs/wave)
    const int sa0 = w * 2, sa1 = w * 2 + 1;
    size_t gaddrA0 = (size_t)(m0 + sa0 * 16 + lr) * K + kc;
    size_t gaddrA1 = (size_t)(m0 + sa1 * 16 + lr) * K + kc;
    size_t gaddrB[4];
    #pragma unroll
    for (int j = 0; j < 4; j++)
        gaddrB[j] = (size_t)(n0 + (w * 4 + j) * 16 + lr) * K + kc;

    GLOAD_LDS16(ybf + gaddrA0, &As[sa0 * 512]);
    GLOAD_LDS16(ybf + gaddrA1, &As[sa1 * 512]);
    #pragma unroll
    for (int j = 0; j < 4; j++)
        GLOAD_LDS16(Wout + gaddrB[j], &Bs[(w * 4 + j) * 512]);

    int buf = 0;
    for (int k0 = 0; k0 < K; k0 += 32) {
        __syncthreads();
        if (k0 + 32 < K) {
            const int nbA = (buf ^ 1) * 2048, nbB = (buf ^ 1) * 4096;
            GLOAD_LDS16(ybf + gaddrA0 + k0 + 32, &As[nbA + sa0 * 512]);
            GLOAD_LDS16(ybf + gaddrA1 + k0 + 32, &As[nbA + sa1 * 512]);
            #pragma unroll
            for (int j = 0; j < 4; j++)
                GLOAD_LDS16(Wout + gaddrB[j] + k0 + 32, &Bs[nbB + (w * 4 + j) * 512]);
        }
        const ushort* as = &As[buf * 2048];
        const ushort* bs = &Bs[buf * 4096];
        bf16x8 af[4], bfv[4];
        #pragma unroll
        for (int t = 0; t < 4; t++) {
            af[t]  = *reinterpret_cast<const bf16x8*>(&as[(t * 16 + fr) * 32 + quad * 8]);
            bfv[t] = *reinterpret_cast<const bf16x8*>(&bs[(wn * 64 + t * 16 + fr) * 32 + quad * 8]);
        }
        #pragma unroll
        for (int i = 0; i < 4; i++)
            #pragma unroll
            for (int j = 0; j < 4; j++)
                acc[i][j] = __builtin_amdgcn_mfma_f32_16x16x32_bf16(af[i], bfv[j], acc[i][j], 0, 0, 0);
        buf ^= 1;
    }

    // epilogue: stage 64x128 f32 tile in LDS, store full lines with +x fused
    float* Sf = (float*)S;
    __syncthreads();
    #pragma unroll
    for (int j = 0; j < 4; j++) {
        int col = wn * 64 + j * 16 + fr;
        float bj = b_out[n0 + col];
        #pragma unroll
        for (int i = 0; i < 4; i++) {
            int row = i * 16 + quad * 4;
            #pragma unroll
            for (int r = 0; r < 4; r++)
                Sf[(row + r) * 128 + col] = acc[i][j][r] + bj;
        }
    }
    __syncthreads();
    #pragma unroll
    for (int k = 0; k < 16; k++) {
        int v = k * 128 + tid;                 // float4 id, 0..2047
        int row = v >> 5, c = (v & 31) * 4;
        size_t off = (size_t)(m0 + row) * D_MODEL + n0 + c;
        float4 xa = *reinterpret_cast<const float4*>(&x[off]);
        float4 cv = *reinterpret_cast<const float4*>(&Sf[v * 4]);
        float4 o = { cv.x + xa.x, cv.y + xa.y, cv.z + xa.z, cv.w + xa.w };
        *reinterpret_cast<float4*>(&resid[off]) = o;
    }
}

// Pass 1 (fused dt-finalize + conv + gate + local scan): per-(b,chunk,h) thread.
__global__ __launch_bounds__(256) void scan_pass1(
    const ushort* __restrict__ u_bf, const ushort* __restrict__ g_bf,
    const float* __restrict__ conv_w, const float* __restrict__ conv_b,
    const float* __restrict__ dt_sum, const float* __restrict__ A_raw,
    const float* __restrict__ B_ssm, const float* __restrict__ C_ssm,
    ushort* __restrict__ ypart, float* __restrict__ states)
{
    int idx = blockIdx.x * 256 + threadIdx.x;
    int h  = idx & (HIDDEN - 1);
    int bc = idx >> 11;
    int c  = bc & (NCHUNK - 1);
    int b  = bc >> 5;
    float dt = fminf(fmaxf(dt_sum[h] * (1.0f / NTOK), 1e-3f), 2.0f);
    float Ad[D_STATE], Bd[D_STATE], Cv[D_STATE], st[D_STATE];
    #pragma unroll
    for (int s = 0; s < D_STATE; s++) {
        float Av = -softplus_f(A_raw[h * D_STATE + s]);
        float a = expf(Av * dt);
        Ad[s] = a;
        Bd[s] = (a - 1.0f) / (Av + 1e-6f) * B_ssm[h * D_STATE + s];
        Cv[s] = C_ssm[h * D_STATE + s];
        st[s] = 0.f;
    }

    float w0 = conv_w[h * 3 + 0], w1 = conv_w[h * 3 + 1];
    float w2 = conv_w[h * 3 + 2], cb = conv_b[h];
    const int tok0 = c * CHUNK;
    const size_t base = ((size_t)b * SEQ + tok0) * HIDDEN + h;
    float u_prev = (tok0 > 0) ? bf2f(u_bf[base - HIDDEN]) : 0.f;
    float u_cur  = bf2f(u_bf[base]);
    for (int l = 0; l < CHUNK; l++) {
        float u_next = (tok0 + l + 1 < SEQ) ? bf2f(u_bf[base + (size_t)(l + 1) * HIDDEN]) : 0.f;
        float gv = bf2f(g_bf[base + (size_t)l * HIDDEN]);
        float conv = u_prev * w0 + u_cur * w1 + u_next * w2 + cb;
        float uv = u_cur * gv + conv * (1.0f - gv);
        float y0 = 0.f, y1 = 0.f, y2 = 0.f, y3 = 0.f;
        #pragma unroll
        for (int s = 0; s < D_STATE; s += 4) {
            st[s+0] = fmaf(Ad[s+0], st[s+0], Bd[s+0] * uv);
            st[s+1] = fmaf(Ad[s+1], st[s+1], Bd[s+1] * uv);
            st[s+2] = fmaf(Ad[s+2], st[s+2], Bd[s+2] * uv);
            st[s+3] = fmaf(Ad[s+3], st[s+3], Bd[s+3] * uv);
            y0 = fmaf(st[s+0], Cv[s+0], y0);
            y1 = fmaf(st[s+1], Cv[s+1], y1);
            y2 = fmaf(st[s+2], Cv[s+2], y2);
            y3 = fmaf(st[s+3], Cv[s+3], y3);
        }
        ypart[base + (size_t)l * HIDDEN] = f2bf((y0 + y1) + (y2 + y3));
        u_prev = u_cur; u_cur = u_next;
    }
    float4* sp = reinterpret_cast<float4*>(states + ((size_t)bc * HIDDEN + h) * D_STATE);
    #pragma unroll
    for (int q = 0; q < 4; q++)
        sp[q] = (float4){st[q*4+0], st[q*4+1], st[q*4+2], st[q*4+3]};
}

// Pass 2: in-place exclusive propagation of chunk-boundary states.
__global__ __launch_bounds__(256) void scan_pass2(
    float* __restrict__ states, const float* __restrict__ dt_sum,
    const float* __restrict__ A_raw)
{
    int idx = blockIdx.x * 256 + threadIdx.x;
    int s = idx & 15;
    int h = (idx >> 4) & (HIDDEN - 1);
    int b = idx >> 15;
    float dt = fminf(fmaxf(dt_sum[h] * (1.0f / NTOK), 1e-3f), 2.0f);
    float Av = -softplus_f(A_raw[h * D_STATE + s]);
    float aL = expf(Av * dt * CHUNK);
    float carry = 0.f;
    for (int c = 0; c < NCHUNK; c++) {
        size_t addr = (((size_t)(b * NCHUNK + c) * HIDDEN) + h) * D_STATE + s;
        float fin = states[addr];
        states[addr] = carry;
        carry = fmaf(aL, carry, fin);
    }
}

// Pass 3: y = ypart + sum_s C*A_d^(l+1)*s_in ; emit bf16 for the out-GEMM.
__global__ __launch_bounds__(256) void scan_pass3(
    const ushort* __restrict__ ypart, const float* __restrict__ states,
    const float* __restrict__ dt_sum, const float* __restrict__ A_raw,
    const float* __restrict__ C_ssm, ushort* __restrict__ ybf)
{
    int idx = blockIdx.x * 256 + threadIdx.x;
    int h  = idx & (HIDDEN - 1);
    int bc = idx >> 11;
    int c  = bc & (NCHUNK - 1);
    int b  = bc >> 5;
    float dt = fminf(fmaxf(dt_sum[h] * (1.0f / NTOK), 1e-3f), 2.0f);
    float Ad[D_STATE], t[D_STATE];
    const float* sp = states + ((size_t)bc * HIDDEN + h) * D_STATE;
    #pragma unroll
    for (int s = 0; s < D_STATE; s++) {
        float Av = -softplus_f(A_raw[h * D_STATE + s]);
        float a = expf(Av * dt);
        Ad[s] = a;
        t[s] = C_ssm[h * D_STATE + s] * a * sp[s];
    }
    const size_t base = ((size_t)b * SEQ + (size_t)c * CHUNK) * HIDDEN + h;
    for (int l = 0; l < CHUNK; l++) {
        float c0 = 0.f, c1 = 0.f;
        #pragma unroll
        for (int s = 0; s < D_STATE; s += 2) {
            c0 += t[s];
            c1 += t[s + 1];
            t[s] *= Ad[s];
            t[s + 1] *= Ad[s + 1];
        }
        ybf[base + (size_t)l * HIDDEN] = f2bf(bf2f(ypart[base + (size_t)l * HIDDEN]) + (c0 + c1));
    }
}

__global__ __launch_bounds__(256) void ln_kernel(
    const float* __restrict__ resid, const float* __restrict__ ln_g,
    const float* __restrict__ ln_b, float* __restrict__ out)
{
    int row = blockIdx.x;
    int tid = threadIdx.x;
    const float4 v = reinterpret_cast<const float4*>(resid + (size_t)row * D_MODEL)[tid];
    float s  = v.x + v.y + v.z + v.w;
    float ss = v.x * v.x + v.y * v.y + v.z * v.z + v.w * v.w;
    #pragma unroll
    for (int off = 32; off > 0; off >>= 1) {
        s  += __shfl_down(s, off);
        ss += __shfl_down(ss, off);
    }
    __shared__ float sbuf[4], ssbuf[4];
    int wid = tid >> 6, lane = tid & 63;
    if (lane == 0) { sbuf[wid] = s; ssbuf[wid] = ss; }
    __syncthreads();
    float tot  = sbuf[0] + sbuf[1] + sbuf[2] + sbuf[3];
    float tot2 = ssbuf[0] + ssbuf[1] + ssbuf[2] + ssbuf[3];
    float mean = tot * (1.0f / D_MODEL);
    float var  = tot2 * (1.0f / D_MODEL) - mean * mean;
    float rstd = rsqrtf(var + 1e-5f);
    const float4 gv = reinterpret_cast<const float4*>(ln_g)[tid];
    const float4 bv = reinterpret_cast<const float4*>(ln_b)[tid];
    float4 o;
    o.x = (v.x - mean) * rstd * gv.x + bv.x;
    o.y = (v.y - mean) * rstd * gv.y + bv.y;
    o.z = (v.z - mean) * rstd * gv.z + bv.z;
    o.w = (v.w - mean) * rstd * gv.w + bv.w;
    reinterpret_cast<float4*>(out + (size_t)row * D_MODEL)[tid] = o;
}

extern "C" void kernel_launch(void* const* d_in, const int* in_sizes, int n_in,
                              void* d_out, int out_size, void* d_ws, size_t ws_size,
                              hipStream_t stream) {
    const float* x      = (const float*)d_in[0];
    const float* W_x    = (const float*)d_in[1];
    const float* b_x    = (const float*)d_in[2];
    const float* W_g    = (const float*)d_in[3];
    const float* b_g    = (const float*)d_in[4];
    const float* conv_w = (const float*)d_in[5];
    const float* conv_b = (const float*)d_in[6];
    const float* A_raw  = (const float*)d_in[7];
    const float* B_ssm  = (const float*)d_in[8];
    const float* C_ssm  = (const float*)d_in[9];
    const float* W_dt   = (const float*)d_in[10];
    const float* b_dt   = (const float*)d_in[11];
    const float* W_out  = (const float*)d_in[12];
    const float* b_out  = (const float*)d_in[13];
    const float* ln_g   = (const float*)d_in[14];
    const float* ln_b   = (const float*)d_in[15];

    char* W = (char*)d_ws;
    ushort* arena   = (ushort*)(W);                    // 24MB: x_bf|Wcat|Wout_bf
    ushort* x_bf    = arena;                           // [4096,1024]
    ushort* Wcat    = arena + 4194304;                 // [6144,1024] (Wx|Wg|Wdt)
    ushort* Wout_bf = arena + 10485760;                // [1024,2048]
    ushort* u_bf    = (ushort*)(W + (24ull << 20));    // 16MB [4096,2048] -> y_bf
    ushort* g_bf    = (ushort*)(W + (40ull << 20));    // 16MB [4096,2048]
    ushort* ypart   = (ushort*)(W + (56ull << 20));    // 16MB bf16 partial y
    float*  resid   = (float*)(W + (40ull << 20));     // 32MB, over g_bf+ypart (dead)
    float*  states  = (float*)(W + (72ull << 20));     // 8MB [B*NC,H,16]
    float*  dt_sum  = (float*)(W + (80ull << 20));     // 8KB
    ushort* y_bf    = u_bf;                            // alias (u dead after pass1)

    hipMemsetAsync(dt_sum, 0, HIDDEN * sizeof(float), stream);

    dim3 blk(256);
    cvt_all<<<12288, blk, 0, stream>>>(x, W_x, W_g, W_dt, W_out, arena);

    dim3 grid_proj(NTOK / 128, 3 * HIDDEN / 128);   // (32 m, 48 n), m fastest
    proj_gemm_fused<<<grid_proj, blk, 0, stream>>>(x_bf, Wcat, b_x, b_g, b_dt,
                                                   u_bf, g_bf, dt_sum);
    scan_pass1<<<(BATCH * NCHUNK * HIDDEN) / 256, blk, 0, stream>>>(
        u_bf, g_bf, conv_w, conv_b, dt_sum, A_raw, B_ssm, C_ssm, ypart, states);
    scan_pass2<<<(BATCH * HIDDEN * D_STATE) / 256, blk, 0, stream>>>(states, dt_sum, A_raw);
    scan_pass3<<<(BATCH * NCHUNK * HIDDEN) / 256, blk, 0, stream>>>(ypart, states, dt_sum,
                                                                    A_raw, C_ssm, y_bf);
    dim3 grid_out(NTOK / 64, D_MODEL / 128);        // (64 m, 8 n), m fastest
    gemm_out<<<grid_out, dim3(128), 0, stream>>>(y_bf, Wout_bf, b_out, x, resid);
    ln_kernel<<<NTOK, blk, 0, stream>>>(resid, ln_g, ln_b, (float*)d_out);
}

// Round 8
// 295.637 us; speedup vs baseline: 1.0933x; 1.0933x over previous
//
#include <hip/hip_runtime.h>
#include <math.h>

#define D_MODEL 1024
#define HIDDEN  2048
#define D_STATE 16
#define BATCH   2
#define SEQ     2048
#define NTOK    (BATCH*SEQ)   // 4096
#define CHUNK   64
#define NCHUNK  (SEQ/CHUNK)   // 32

typedef __attribute__((ext_vector_type(8))) short bf16x8;
typedef __attribute__((ext_vector_type(8))) unsigned short ushort8;
typedef __attribute__((ext_vector_type(4))) float f32x4;

#define GLOAD_LDS16(gptr, lptr) \
    __builtin_amdgcn_global_load_lds((const __attribute__((address_space(1))) void*)(gptr), \
                                     (__attribute__((address_space(3))) void*)(lptr), 16, 0, 0)

__device__ __forceinline__ float softplus_f(float x) {
    return fmaxf(x, 0.0f) + log1pf(expf(-fabsf(x)));
}
__device__ __forceinline__ float sigmoid_f(float x) {
    return 1.0f / (1.0f + expf(-x));
}
__device__ __forceinline__ ushort f2bf(float f) {      // RNE fp32->bf16
    unsigned u = __float_as_uint(f);
    unsigned r = (u + 0x7fffu + ((u >> 16) & 1u)) >> 16;
    return (ushort)r;
}
__device__ __forceinline__ float bf2f(ushort u) {
    return __uint_as_float(((unsigned)u) << 16);
}

// Converts x, W_x, W_g, W_dt, W_out into a contiguous bf16 arena.
__global__ __launch_bounds__(256) void cvt_all(
    const float* __restrict__ x, const float* __restrict__ Wx,
    const float* __restrict__ Wg, const float* __restrict__ Wdt,
    const float* __restrict__ Wout, ushort* __restrict__ arena)
{
    int i = blockIdx.x * 256 + threadIdx.x;   // float4 index, total 3145728
    const float* src; int base;
    if      (i < 1048576) { src = x;    base = 0; }
    else if (i < 1572864) { src = Wx;   base = 1048576; }
    else if (i < 2097152) { src = Wg;   base = 1572864; }
    else if (i < 2621440) { src = Wdt;  base = 2097152; }
    else                  { src = Wout; base = 2621440; }
    float4 v = reinterpret_cast<const float4*>(src)[i - base];
    ushort4 o = { f2bf(v.x), f2bf(v.y), f2bf(v.z), f2bf(v.w) };
    reinterpret_cast<ushort4*>(arena)[i] = o;
}

// 3-stage pipelined 128x128 K-loop (4 waves), BK=32.
// 3 LDS buffers/operand; loads issued 2 iters ahead; per-iter barrier waits
// vmcnt(4) (own newest 4 prefetch loads may fly) AND lgkmcnt(0) (all own
// ds_reads of the previous set complete BEFORE the barrier -- without this,
// in-flight ds_reads race the prefetch overwriting their buffer; R7 bug).
__device__ __forceinline__ void kloop_pipe3(
    const ushort* __restrict__ A, const ushort* __restrict__ B,
    int K, int m0, int n0, ushort* As, ushort* Bs,
    f32x4 (&acc)[4][4], int lane, int w, int wm, int wn)
{
    const int lr   = lane >> 2;
    const int kc   = (lane & 3) * 8;
    const int quad = lane >> 4;
    const int fr   = lane & 15;

    const int slab0 = w * 2;
    const int r0 = slab0 * 16 + lr;
    const int r1 = r0 + 16;
    const size_t ga0 = (size_t)(m0 + r0) * K + kc;
    const size_t ga1 = (size_t)(m0 + r1) * K + kc;
    const size_t gb0 = (size_t)(n0 + r0) * K + kc;
    const size_t gb1 = (size_t)(n0 + r1) * K + kc;

    const int niter = K / 32;
    // prologue: sets 0 and 1
    GLOAD_LDS16(A + ga0,      &As[slab0 * 512]);
    GLOAD_LDS16(A + ga1,      &As[slab0 * 512 + 512]);
    GLOAD_LDS16(B + gb0,      &Bs[slab0 * 512]);
    GLOAD_LDS16(B + gb1,      &Bs[slab0 * 512 + 512]);
    GLOAD_LDS16(A + ga0 + 32, &As[4096 + slab0 * 512]);
    GLOAD_LDS16(A + ga1 + 32, &As[4096 + slab0 * 512 + 512]);
    GLOAD_LDS16(B + gb0 + 32, &Bs[4096 + slab0 * 512]);
    GLOAD_LDS16(B + gb1 + 32, &Bs[4096 + slab0 * 512 + 512]);

    int buf = 0;
    for (int i = 0; i < niter; i++) {
        // oldest 4 loads (this iter's tile) done; newest 4 may fly; all own
        // LDS reads (previous set) complete so prefetch can't race them.
        asm volatile("s_waitcnt vmcnt(4) lgkmcnt(0)" ::: "memory");
        asm volatile("s_barrier" ::: "memory");
        // issue set i+2 (dummy k=0 when past the end; target buf never read)
        int nb = buf + 2; if (nb >= 3) nb -= 3;
        const size_t koff = (i + 2 < niter) ? (size_t)(i + 2) * 32 : 0;
        GLOAD_LDS16(A + ga0 + koff, &As[nb * 4096 + slab0 * 512]);
        GLOAD_LDS16(A + ga1 + koff, &As[nb * 4096 + slab0 * 512 + 512]);
        GLOAD_LDS16(B + gb0 + koff, &Bs[nb * 4096 + slab0 * 512]);
        GLOAD_LDS16(B + gb1 + koff, &Bs[nb * 4096 + slab0 * 512 + 512]);

        const ushort* as = &As[buf * 4096];
        const ushort* bs = &Bs[buf * 4096];
        bf16x8 af[4], bfv[4];
        #pragma unroll
        for (int t = 0; t < 4; t++) {
            af[t]  = *reinterpret_cast<const bf16x8*>(&as[(wm * 64 + t * 16 + fr) * 32 + quad * 8]);
            bfv[t] = *reinterpret_cast<const bf16x8*>(&bs[(wn * 64 + t * 16 + fr) * 32 + quad * 8]);
        }
        #pragma unroll
        for (int ii = 0; ii < 4; ii++)
            #pragma unroll
            for (int jj = 0; jj < 4; jj++)
                acc[ii][jj] = __builtin_amdgcn_mfma_f32_16x16x32_bf16(af[ii], bfv[jj], acc[ii][jj], 0, 0, 0);
        buf = (buf == 2) ? 0 : buf + 1;
    }
    // drain everything (incl. dummies + LDS ops) before LDS reuse in epilogue
    asm volatile("s_waitcnt vmcnt(0) lgkmcnt(0)" ::: "memory");
    asm volatile("s_barrier" ::: "memory");
}

// Fused projection GEMM: A = x_bf [NTOK,1024], B = Wcat [6144,1024].
// m-fast grid. Regions: [0,2048)->u, [2048,4096)->sigmoid->g, [4096,6144)->dt.
__global__ __launch_bounds__(256) void proj_gemm_fused(
    const ushort* __restrict__ xbf, const ushort* __restrict__ Wcat,
    const float* __restrict__ b_x, const float* __restrict__ b_g,
    const float* __restrict__ b_dt, ushort* __restrict__ u_out,
    ushort* __restrict__ g_out, float* __restrict__ dt_sum)
{
    __shared__ ushort S[24576];            // 48KB: As(3buf)|Bs(3buf); epi reuses
    ushort* As = S;
    ushort* Bs = S + 12288;
    const int tid = threadIdx.x, lane = tid & 63, w = tid >> 6;
    const int wm = w & 1, wn = w >> 1;
    const int m0 = blockIdx.x * 128, n0 = blockIdx.y * 128;   // m-fast
    const int quad = lane >> 4, fr = lane & 15;

    f32x4 acc[4][4];
    #pragma unroll
    for (int i = 0; i < 4; i++)
        #pragma unroll
        for (int j = 0; j < 4; j++)
            acc[i][j] = (f32x4){0.f, 0.f, 0.f, 0.f};

    kloop_pipe3(xbf, Wcat, D_MODEL, m0, n0, As, Bs, acc, lane, w, wm, wn);

    const int region = n0 >> 11;           // 0:u 1:g 2:dt
    const int ncb = n0 & 2047;

    if (region == 2) {
        #pragma unroll
        for (int j = 0; j < 4; j++) {
            int n = ncb + wn * 64 + j * 16 + fr;
            float bj = b_dt[n];
            float s = 0.f;
            #pragma unroll
            for (int i = 0; i < 4; i++)
                #pragma unroll
                for (int r = 0; r < 4; r++)
                    s += softplus_f(acc[i][j][r] + bj);
            s += __shfl_xor(s, 16);
            s += __shfl_xor(s, 32);
            if (lane < 16) atomicAdd(&dt_sum[n], s);
        }
    } else {
        const float* bias = region ? b_g : b_x;
        ushort* out = region ? g_out : u_out;
        ushort* Cs = S;                    // [128][128] bf16 = 32KB (fits 48KB)
        #pragma unroll
        for (int j = 0; j < 4; j++) {
            int col = wn * 64 + j * 16 + fr;
            float bj = bias[ncb + col];
            #pragma unroll
            for (int i = 0; i < 4; i++) {
                int row = wm * 64 + i * 16 + quad * 4;
                #pragma unroll
                for (int r = 0; r < 4; r++) {
                    float v = acc[i][j][r] + bj;
                    if (region) v = sigmoid_f(v);
                    Cs[(row + r) * 128 + col] = f2bf(v);
                }
            }
        }
        __syncthreads();
        #pragma unroll
        for (int k = 0; k < 8; k++) {
            int v = k * 256 + tid;
            int row = v >> 4, c = (v & 15) * 8;
            *reinterpret_cast<ushort8*>(&out[(size_t)(m0 + row) * HIDDEN + ncb + c]) =
                *reinterpret_cast<const ushort8*>(&Cs[v * 8]);
        }
    }
}

// Out projection: A = y_bf [NTOK,2048], B = Wout_bf [1024,2048];
// resid = C + b_out + x (fp32). Two-phase LDS-staged epilogue (full lines).
__global__ __launch_bounds__(256) void gemm_out(
    const ushort* __restrict__ ybf, const ushort* __restrict__ Wout,
    const float* __restrict__ b_out, const float* __restrict__ x,
    float* __restrict__ resid)
{
    __shared__ ushort S[24576];
    ushort* As = S;
    ushort* Bs = S + 12288;
    const int tid = threadIdx.x, lane = tid & 63, w = tid >> 6;
    const int wm = w & 1, wn = w >> 1;
    const int m0 = blockIdx.x * 128, n0 = blockIdx.y * 128;   // m-fast
    const int quad = lane >> 4, fr = lane & 15;

    f32x4 acc[4][4];
    #pragma unroll
    for (int i = 0; i < 4; i++)
        #pragma unroll
        for (int j = 0; j < 4; j++)
            acc[i][j] = (f32x4){0.f, 0.f, 0.f, 0.f};

    kloop_pipe3(ybf, Wout, HIDDEN, m0, n0, As, Bs, acc, lane, w, wm, wn);

    float* Sf = (float*)S;                  // [64][128] f32 = 32KB per phase
    #pragma unroll
    for (int phase = 0; phase < 2; phase++) {
        if (wm == phase) {
            #pragma unroll
            for (int j = 0; j < 4; j++) {
                int col = wn * 64 + j * 16 + fr;
                float bj = b_out[n0 + col];
                #pragma unroll
                for (int i = 0; i < 4; i++) {
                    int row = i * 16 + quad * 4;
                    #pragma unroll
                    for (int r = 0; r < 4; r++)
                        Sf[(row + r) * 128 + col] = acc[i][j][r] + bj;
                }
            }
        }
        __syncthreads();
        #pragma unroll
        for (int k = 0; k < 8; k++) {
            int v = k * 256 + tid;                 // float4 id, 0..2047
            int row = v >> 5, c = (v & 31) * 4;
            size_t off = (size_t)(m0 + phase * 64 + row) * D_MODEL + n0 + c;
            float4 xa = *reinterpret_cast<const float4*>(&x[off]);
            float4 cv = *reinterpret_cast<const float4*>(&Sf[v * 4]);
            float4 o = { cv.x + xa.x, cv.y + xa.y, cv.z + xa.z, cv.w + xa.w };
            *reinterpret_cast<float4*>(&resid[off]) = o;
        }
        __syncthreads();
    }
}

__global__ __launch_bounds__(256) void dt_finalize(
    const float* __restrict__ dt_sum, const float* __restrict__ A_raw,
    const float* __restrict__ B_ssm, float* __restrict__ A_d,
    float* __restrict__ B_d, float* __restrict__ A_dL)
{
    int i = blockIdx.x * 256 + threadIdx.x;
    if (i >= HIDDEN * D_STATE) return;
    int h = i >> 4;
    float dt = dt_sum[h] * (1.0f / NTOK);
    dt = fminf(fmaxf(dt, 1e-3f), 2.0f);
    float Av = -softplus_f(A_raw[i]);
    float Ad = expf(Av * dt);
    float Bd = (Ad - 1.0f) / (Av + 1e-6f) * B_ssm[i];
    A_d[i] = Ad;
    B_d[i] = Bd;
    A_dL[i] = expf(Av * dt * CHUNK);
}

// Pass 1 (fused conv + gate + local scan): per-(b,chunk,h) thread.
__global__ __launch_bounds__(256) void scan_pass1(
    const ushort* __restrict__ u_bf, const ushort* __restrict__ g_bf,
    const float* __restrict__ conv_w, const float* __restrict__ conv_b,
    const float* __restrict__ A_d, const float* __restrict__ B_d,
    const float* __restrict__ C_ssm,
    ushort* __restrict__ ypart, float* __restrict__ states)
{
    int idx = blockIdx.x * 256 + threadIdx.x;
    int h  = idx & (HIDDEN - 1);
    int bc = idx >> 11;
    int c  = bc & (NCHUNK - 1);
    int b  = bc >> 5;
    float Ad[D_STATE], Bd[D_STATE], Cv[D_STATE], st[D_STATE];
    const float4* a4 = reinterpret_cast<const float4*>(A_d  + h * D_STATE);
    const float4* b4 = reinterpret_cast<const float4*>(B_d  + h * D_STATE);
    const float4* c4 = reinterpret_cast<const float4*>(C_ssm + h * D_STATE);
    #pragma unroll
    for (int q = 0; q < 4; q++) {
        float4 av = a4[q], bv = b4[q], cv = c4[q];
        Ad[q*4+0]=av.x; Ad[q*4+1]=av.y; Ad[q*4+2]=av.z; Ad[q*4+3]=av.w;
        Bd[q*4+0]=bv.x; Bd[q*4+1]=bv.y; Bd[q*4+2]=bv.z; Bd[q*4+3]=bv.w;
        Cv[q*4+0]=cv.x; Cv[q*4+1]=cv.y; Cv[q*4+2]=cv.z; Cv[q*4+3]=cv.w;
    }
    #pragma unroll
    for (int s = 0; s < D_STATE; s++) st[s] = 0.f;

    float w0 = conv_w[h * 3 + 0], w1 = conv_w[h * 3 + 1];
    float w2 = conv_w[h * 3 + 2], cb = conv_b[h];
    const int tok0 = c * CHUNK;
    const size_t base = ((size_t)b * SEQ + tok0) * HIDDEN + h;
    float u_prev = (tok0 > 0) ? bf2f(u_bf[base - HIDDEN]) : 0.f;
    float u_cur  = bf2f(u_bf[base]);
    for (int l = 0; l < CHUNK; l++) {
        float u_next = (tok0 + l + 1 < SEQ) ? bf2f(u_bf[base + (size_t)(l + 1) * HIDDEN]) : 0.f;
        float gv = bf2f(g_bf[base + (size_t)l * HIDDEN]);
        float conv = u_prev * w0 + u_cur * w1 + u_next * w2 + cb;
        float uv = u_cur * gv + conv * (1.0f - gv);
        float y0 = 0.f, y1 = 0.f, y2 = 0.f, y3 = 0.f;
        #pragma unroll
        for (int s = 0; s < D_STATE; s += 4) {
            st[s+0] = fmaf(Ad[s+0], st[s+0], Bd[s+0] * uv);
            st[s+1] = fmaf(Ad[s+1], st[s+1], Bd[s+1] * uv);
            st[s+2] = fmaf(Ad[s+2], st[s+2], Bd[s+2] * uv);
            st[s+3] = fmaf(Ad[s+3], st[s+3], Bd[s+3] * uv);
            y0 = fmaf(st[s+0], Cv[s+0], y0);
            y1 = fmaf(st[s+1], Cv[s+1], y1);
            y2 = fmaf(st[s+2], Cv[s+2], y2);
            y3 = fmaf(st[s+3], Cv[s+3], y3);
        }
        ypart[base + (size_t)l * HIDDEN] = f2bf((y0 + y1) + (y2 + y3));
        u_prev = u_cur; u_cur = u_next;
    }
    float4* sp = reinterpret_cast<float4*>(states + ((size_t)bc * HIDDEN + h) * D_STATE);
    #pragma unroll
    for (int q = 0; q < 4; q++)
        sp[q] = (float4){st[q*4+0], st[q*4+1], st[q*4+2], st[q*4+3]};
}

// Pass 2: in-place exclusive propagation of chunk-boundary states.
__global__ __launch_bounds__(256) void scan_pass2(
    float* __restrict__ states, const float* __restrict__ A_dL)
{
    int idx = blockIdx.x * 256 + threadIdx.x;
    int s = idx & 15;
    int h = (idx >> 4) & (HIDDEN - 1);
    int b = idx >> 15;
    float aL = A_dL[h * D_STATE + s];
    float carry = 0.f;
    for (int c = 0; c < NCHUNK; c++) {
        size_t addr = (((size_t)(b * NCHUNK + c) * HIDDEN) + h) * D_STATE + s;
        float fin = states[addr];
        states[addr] = carry;
        carry = fmaf(aL, carry, fin);
    }
}

// Pass 3: y = ypart + sum_s C*A_d^(l+1)*s_in ; emit bf16 for the out-GEMM.
__global__ __launch_bounds__(256) void scan_pass3(
    const ushort* __restrict__ ypart, const float* __restrict__ states,
    const float* __restrict__ A_d, const float* __restrict__ C_ssm,
    ushort* __restrict__ ybf)
{
    int idx = blockIdx.x * 256 + threadIdx.x;
    int h  = idx & (HIDDEN - 1);
    int bc = idx >> 11;
    int c  = bc & (NCHUNK - 1);
    int b  = bc >> 5;
    float Ad[D_STATE], t[D_STATE];
    const float* sp = states + ((size_t)bc * HIDDEN + h) * D_STATE;
    #pragma unroll
    for (int s = 0; s < D_STATE; s++) {
        float a = A_d[h * D_STATE + s];
        Ad[s] = a;
        t[s] = C_ssm[h * D_STATE + s] * a * sp[s];
    }
    const size_t base = ((size_t)b * SEQ + (size_t)c * CHUNK) * HIDDEN + h;
    for (int l = 0; l < CHUNK; l++) {
        float c0 = 0.f, c1 = 0.f;
        #pragma unroll
        for (int s = 0; s < D_STATE; s += 2) {
            c0 += t[s];
            c1 += t[s + 1];
            t[s] *= Ad[s];
            t[s + 1] *= Ad[s + 1];
        }
        ybf[base + (size_t)l * HIDDEN] = f2bf(bf2f(ypart[base + (size_t)l * HIDDEN]) + (c0 + c1));
    }
}

__global__ __launch_bounds__(256) void ln_kernel(
    const float* __restrict__ resid, const float* __restrict__ ln_g,
    const float* __restrict__ ln_b, float* __restrict__ out)
{
    int row = blockIdx.x;
    int tid = threadIdx.x;
    const float4 v = reinterpret_cast<const float4*>(resid + (size_t)row * D_MODEL)[tid];
    float s  = v.x + v.y + v.z + v.w;
    float ss = v.x * v.x + v.y * v.y + v.z * v.z + v.w * v.w;
    #pragma unroll
    for (int off = 32; off > 0; off >>= 1) {
        s  += __shfl_down(s, off);
        ss += __shfl_down(ss, off);
    }
    __shared__ float sbuf[4], ssbuf[4];
    int wid = tid >> 6, lane = tid & 63;
    if (lane == 0) { sbuf[wid] = s; ssbuf[wid] = ss; }
    __syncthreads();
    float tot  = sbuf[0] + sbuf[1] + sbuf[2] + sbuf[3];
    float tot2 = ssbuf[0] + ssbuf[1] + ssbuf[2] + ssbuf[3];
    float mean = tot * (1.0f / D_MODEL);
    float var  = tot2 * (1.0f / D_MODEL) - mean * mean;
    float rstd = rsqrtf(var + 1e-5f);
    const float4 gv = reinterpret_cast<const float4*>(ln_g)[tid];
    const float4 bv = reinterpret_cast<const float4*>(ln_b)[tid];
    float4 o;
    o.x = (v.x - mean) * rstd * gv.x + bv.x;
    o.y = (v.y - mean) * rstd * gv.y + bv.y;
    o.z = (v.z - mean) * rstd * gv.z + bv.z;
    o.w = (v.w - mean) * rstd * gv.w + bv.w;
    reinterpret_cast<float4*>(out + (size_t)row * D_MODEL)[tid] = o;
}

extern "C" void kernel_launch(void* const* d_in, const int* in_sizes, int n_in,
                              void* d_out, int out_size, void* d_ws, size_t ws_size,
                              hipStream_t stream) {
    const float* x      = (const float*)d_in[0];
    const float* W_x    = (const float*)d_in[1];
    const float* b_x    = (const float*)d_in[2];
    const float* W_g    = (const float*)d_in[3];
    const float* b_g    = (const float*)d_in[4];
    const float* conv_w = (const float*)d_in[5];
    const float* conv_b = (const float*)d_in[6];
    const float* A_raw  = (const float*)d_in[7];
    const float* B_ssm  = (const float*)d_in[8];
    const float* C_ssm  = (const float*)d_in[9];
    const float* W_dt   = (const float*)d_in[10];
    const float* b_dt   = (const float*)d_in[11];
    const float* W_out  = (const float*)d_in[12];
    const float* b_out  = (const float*)d_in[13];
    const float* ln_g   = (const float*)d_in[14];
    const float* ln_b   = (const float*)d_in[15];

    char* W = (char*)d_ws;
    ushort* arena   = (ushort*)(W);                    // 24MB: x_bf|Wcat|Wout_bf
    ushort* x_bf    = arena;                           // [4096,1024]
    ushort* Wcat    = arena + 4194304;                 // [6144,1024] (Wx|Wg|Wdt)
    ushort* Wout_bf = arena + 10485760;                // [1024,2048]
    ushort* u_bf    = (ushort*)(W + (24ull << 20));    // 16MB [4096,2048] -> y_bf
    ushort* g_bf    = (ushort*)(W + (40ull << 20));    // 16MB [4096,2048]
    ushort* ypart   = (ushort*)(W + (56ull << 20));    // 16MB bf16 partial y
    float*  resid   = (float*)(W + (40ull << 20));     // 32MB, over g_bf+ypart (dead)
    float*  states  = (float*)(W + (72ull << 20));     // 8MB [B*NC,H,16]
    float*  dt_sum  = (float*)(W + (80ull << 20));     // 8KB
    float*  A_d     = (float*)(W + (80ull << 20) + 65536);
    float*  B_d     = (float*)(W + (80ull << 20) + 65536 + 131072);
    float*  A_dL    = (float*)(W + (80ull << 20) + 65536 + 262144);
    ushort* y_bf    = u_bf;                            // alias (u dead after pass1)

    hipMemsetAsync(dt_sum, 0, HIDDEN * sizeof(float), stream);

    dim3 blk(256);
    cvt_all<<<12288, blk, 0, stream>>>(x, W_x, W_g, W_dt, W_out, arena);

    dim3 grid_proj(NTOK / 128, 3 * HIDDEN / 128);   // (32 m, 48 n), m fastest
    proj_gemm_fused<<<grid_proj, blk, 0, stream>>>(x_bf, Wcat, b_x, b_g, b_dt,
                                                   u_bf, g_bf, dt_sum);
    dt_finalize<<<(HIDDEN * D_STATE) / 256, blk, 0, stream>>>(dt_sum, A_raw, B_ssm,
                                                              A_d, B_d, A_dL);
    scan_pass1<<<(BATCH * NCHUNK * HIDDEN) / 256, blk, 0, stream>>>(
        u_bf, g_bf, conv_w, conv_b, A_d, B_d, C_ssm, ypart, states);
    scan_pass2<<<(BATCH * HIDDEN * D_STATE) / 256, blk, 0, stream>>>(states, A_dL);
    scan_pass3<<<(BATCH * NCHUNK * HIDDEN) / 256, blk, 0, stream>>>(ypart, states, A_d,
                                                                    C_ssm, y_bf);
    dim3 grid_out(NTOK / 128, D_MODEL / 128);       // (32 m, 8 n), m fastest
    gemm_out<<<grid_out, blk, 0, stream>>>(y_bf, Wout_bf, b_out, x, resid);
    ln_kernel<<<NTOK, blk, 0, stream>>>(resid, ln_g, ln_b, (float*)d_out);
}